// Round 11
// baseline (200.556 us; speedup 1.0000x reference)
//
#include <hip/hip_runtime.h>
#include <cstdint>
#include <cstddef>

#define BATCH 16384
#define VOCAB_MASK (4194304 - 1)

typedef __attribute__((ext_vector_type(4))) float f32x4;
typedef __attribute__((ext_vector_type(8))) __bf16 bf16x8;
typedef __attribute__((ext_vector_type(4))) __bf16 bf16x4;

static_assert(sizeof(bf16x8) == 16, "bf16x8 must be 16 bytes");

static __device__ __forceinline__ __bf16 f2bf(float f) {
  union { float f; unsigned u; } in; in.f = f;
  unsigned r = in.u + 0x7FFF + ((in.u >> 16) & 1);
  union { unsigned short s; __bf16 b; } out; out.s = (unsigned short)(r >> 16);
  return out.b;
}
static __device__ __forceinline__ float bf2f(__bf16 b) {
  union { __bf16 b; unsigned short s; } in; in.b = b;
  union { unsigned u; float f; } out; out.u = ((unsigned)in.s) << 16;
  return out.f;
}

// async global->LDS, 16B per lane. LDS dest must be wave-uniform base + lane*16.
#define GLDS16(g, l) __builtin_amdgcn_global_load_lds( \
    (const __attribute__((address_space(1))) unsigned int*)(g), \
    (__attribute__((address_space(3))) unsigned int*)(l), 16, 0, 0)

// swizzle: XOR 16B-chunk index bits (involution)
static __device__ __forceinline__ unsigned swz16(unsigned b) {
  return b ^ ((((b >> 6) & 3u) ^ ((b >> 8) & 3u)) << 4);
}
static __device__ __forceinline__ bf16x8 lds_frag(const char* smem, unsigned base,
                                                  unsigned r, unsigned cg) {
  unsigned b = r * 64u + cg;
  return *(const bf16x8*)(smem + base + swz16(b));
}

// ---------------- fused weight transpose + bf16 convert: WT[n][k] = W[k][n] ----------------
struct TJob { const float* W; __bf16* WT; int K, N, Kp, tx, off; };
struct TJobs { TJob j[7]; };

__global__ __launch_bounds__(256) void transpose_all(TJobs js, int njobs)
{
  __shared__ float tile[64][65];
  int b = blockIdx.x;
  int ji = 0;
  #pragma unroll
  for (int i = 1; i < 7; ++i) if (i < njobs && b >= js.j[i].off) ji = i;
  const TJob jb = js.j[ji];
  int lb = b - jb.off;
  int bx = lb % jb.tx, by = lb / jb.tx;
  const int kb = bx * 64, nb = by * 64;
  const int tx = threadIdx.x & 63, ty = threadIdx.x >> 6;
  #pragma unroll
  for (int i = 0; i < 64; i += 4) {
    int k = kb + ty + i, n = nb + tx;
    tile[ty + i][tx] = (k < jb.K && n < jb.N) ? jb.W[(size_t)k * jb.N + n] : 0.f;
  }
  __syncthreads();
  #pragma unroll
  for (int i = 0; i < 64; i += 4) {
    int n = nb + ty + i, k = kb + tx;
    if (n < jb.N && k < jb.Kp) jb.WT[(size_t)n * jb.Kp + k] = f2bf(tile[tx][ty + i]);
  }
}

// ---------------- fused bottom MLP: x(13) -> 512 -> 256 -> 128 ----------------
__global__ __launch_bounds__(256) void bottom_fused(
    const float* __restrict__ x,
    const __bf16* __restrict__ w0t, const float* __restrict__ b0,
    const __bf16* __restrict__ w1t, const float* __restrict__ b1,
    const __bf16* __restrict__ w2t, const float* __restrict__ b2,
    __bf16* __restrict__ h2out)
{
  __shared__ __bf16 h0s[32][520];
  __shared__ __bf16 h1s[32][264];
  __shared__ __bf16 As[32][40];
  const int tid = threadIdx.x, lane = tid & 63, w = tid >> 6;
  const int r0 = blockIdx.x * 32;
  const unsigned rA = lane & 15, cgw = (lane >> 4) * 8;

  for (int idx = tid; idx < 32 * 40; idx += 256) {
    int row = idx / 40, k = idx - row * 40;
    float v = (k < 13) ? x[(size_t)(r0 + row) * 13 + k] : 0.f;
    As[row][k] = f2bf(v);
  }
  __syncthreads();

  bf16x8 a00 = *(const bf16x8*)&As[rA][cgw];
  bf16x8 a01 = *(const bf16x8*)&As[rA + 16][cgw];
  #pragma unroll
  for (int p = 0; p < 2; ++p) {
    bf16x8 bv[4];
    #pragma unroll
    for (int n = 0; n < 4; ++n)
      bv[n] = *(const bf16x8*)(w0t + (size_t)(p * 256 + w * 64 + n * 16 + rA) * 32 + cgw);
    f32x4 acc[2][4] = {};
    #pragma unroll
    for (int n = 0; n < 4; ++n) {
      acc[0][n] = __builtin_amdgcn_mfma_f32_16x16x32_bf16(a00, bv[n], acc[0][n], 0, 0, 0);
      acc[1][n] = __builtin_amdgcn_mfma_f32_16x16x32_bf16(a01, bv[n], acc[1][n], 0, 0, 0);
    }
    #pragma unroll
    for (int m = 0; m < 2; ++m)
      #pragma unroll
      for (int n = 0; n < 4; ++n) {
        int col = p * 256 + w * 64 + n * 16 + (int)rA;
        float bb = b0[col];
        #pragma unroll
        for (int r = 0; r < 4; ++r) {
          int row = m * 16 + (lane >> 4) * 4 + r;
          h0s[row][col] = f2bf(fmaxf(acc[m][n][r] + bb, 0.f));
        }
      }
  }
  __syncthreads();

  f32x4 acc1[2][4] = {};
  const __bf16* w1p = w1t + (size_t)(w * 64 + rA) * 512 + cgw;
  bf16x8 c0 = *(const bf16x8*)(w1p + 0 * 8192);
  bf16x8 c1 = *(const bf16x8*)(w1p + 1 * 8192);
  bf16x8 c2 = *(const bf16x8*)(w1p + 2 * 8192);
  bf16x8 c3 = *(const bf16x8*)(w1p + 3 * 8192);
  for (int k0 = 0; k0 < 512; k0 += 32) {
    bf16x8 n0v, n1v, n2v, n3v;
    const bool more = (k0 + 32 < 512);
    if (more) {
      n0v = *(const bf16x8*)(w1p + 0 * 8192 + k0 + 32);
      n1v = *(const bf16x8*)(w1p + 1 * 8192 + k0 + 32);
      n2v = *(const bf16x8*)(w1p + 2 * 8192 + k0 + 32);
      n3v = *(const bf16x8*)(w1p + 3 * 8192 + k0 + 32);
    }
    bf16x8 av0 = *(const bf16x8*)&h0s[rA][k0 + cgw];
    bf16x8 av1 = *(const bf16x8*)&h0s[rA + 16][k0 + cgw];
    acc1[0][0] = __builtin_amdgcn_mfma_f32_16x16x32_bf16(av0, c0, acc1[0][0], 0, 0, 0);
    acc1[1][0] = __builtin_amdgcn_mfma_f32_16x16x32_bf16(av1, c0, acc1[1][0], 0, 0, 0);
    acc1[0][1] = __builtin_amdgcn_mfma_f32_16x16x32_bf16(av0, c1, acc1[0][1], 0, 0, 0);
    acc1[1][1] = __builtin_amdgcn_mfma_f32_16x16x32_bf16(av1, c1, acc1[1][1], 0, 0, 0);
    acc1[0][2] = __builtin_amdgcn_mfma_f32_16x16x32_bf16(av0, c2, acc1[0][2], 0, 0, 0);
    acc1[1][2] = __builtin_amdgcn_mfma_f32_16x16x32_bf16(av1, c2, acc1[1][2], 0, 0, 0);
    acc1[0][3] = __builtin_amdgcn_mfma_f32_16x16x32_bf16(av0, c3, acc1[0][3], 0, 0, 0);
    acc1[1][3] = __builtin_amdgcn_mfma_f32_16x16x32_bf16(av1, c3, acc1[1][3], 0, 0, 0);
    if (more) { c0 = n0v; c1 = n1v; c2 = n2v; c3 = n3v; }
  }
  #pragma unroll
  for (int m = 0; m < 2; ++m)
    #pragma unroll
    for (int n = 0; n < 4; ++n) {
      int col = w * 64 + n * 16 + (int)rA;
      float bb = b1[col];
      #pragma unroll
      for (int r = 0; r < 4; ++r) {
        int row = m * 16 + (lane >> 4) * 4 + r;
        h1s[row][col] = f2bf(fmaxf(acc1[m][n][r] + bb, 0.f));
      }
    }
  __syncthreads();

  f32x4 acc2[2][2] = {};
  const __bf16* w2p = w2t + (size_t)(w * 32 + rA) * 256 + cgw;
  bf16x8 d0 = *(const bf16x8*)(w2p + 0);
  bf16x8 d1 = *(const bf16x8*)(w2p + 4096);
  for (int k0 = 0; k0 < 256; k0 += 32) {
    bf16x8 e0, e1;
    const bool more = (k0 + 32 < 256);
    if (more) {
      e0 = *(const bf16x8*)(w2p + k0 + 32);
      e1 = *(const bf16x8*)(w2p + 4096 + k0 + 32);
    }
    bf16x8 av0 = *(const bf16x8*)&h1s[rA][k0 + cgw];
    bf16x8 av1 = *(const bf16x8*)&h1s[rA + 16][k0 + cgw];
    acc2[0][0] = __builtin_amdgcn_mfma_f32_16x16x32_bf16(av0, d0, acc2[0][0], 0, 0, 0);
    acc2[1][0] = __builtin_amdgcn_mfma_f32_16x16x32_bf16(av1, d0, acc2[1][0], 0, 0, 0);
    acc2[0][1] = __builtin_amdgcn_mfma_f32_16x16x32_bf16(av0, d1, acc2[0][1], 0, 0, 0);
    acc2[1][1] = __builtin_amdgcn_mfma_f32_16x16x32_bf16(av1, d1, acc2[1][1], 0, 0, 0);
    if (more) { d0 = e0; d1 = e1; }
  }
  #pragma unroll
  for (int m = 0; m < 2; ++m)
    #pragma unroll
    for (int n = 0; n < 2; ++n) {
      int col = w * 32 + n * 16 + (int)rA;
      float bb = b2[col];
      #pragma unroll
      for (int r = 0; r < 4; ++r) {
        int row = m * 16 + (lane >> 4) * 4 + r;
        h2out[(size_t)(r0 + row) * 128 + col] = f2bf(fmaxf(acc2[m][n][r] + bb, 0.f));
      }
    }
}

// ---------------- embedding gather (float4) + MFMA interaction, coalesced stores ----------
__global__ __launch_bounds__(256) void interact_mfma(
    const __bf16* __restrict__ bot, const int* __restrict__ xcat,
    const float* __restrict__ emb, __bf16* __restrict__ top_in)
{
  __shared__ __bf16 st[4][32][136];
  const int tid = threadIdx.x, lane = tid & 63, w = tid >> 6;
  const int s = blockIdx.x * 4 + w;

  const int* xr = xcat + (size_t)s * 26;
  float4 buf[13];
  #pragma unroll
  for (int i = 0; i < 13; ++i) {
    int fi = 2 * i + (lane >> 5);
    int ridx = xr[fi] & VOCAB_MASK;
    buf[i] = *(const float4*)(emb + (size_t)ridx * 128 + (lane & 31) * 4);
  }

  *(unsigned*)&st[w][0][lane * 2] = *(const unsigned*)(bot + (size_t)s * 128 + lane * 2);
  #pragma unroll
  for (int r = 27; r < 32; ++r) *(unsigned*)&st[w][r][lane * 2] = 0u;
  #pragma unroll
  for (int i = 0; i < 13; ++i) {
    int row = 1 + 2 * i + (lane >> 5);
    bf16x4 bv;
    bv[0] = f2bf(buf[i].x); bv[1] = f2bf(buf[i].y);
    bv[2] = f2bf(buf[i].z); bv[3] = f2bf(buf[i].w);
    *(bf16x4*)&st[w][row][(lane & 31) * 4] = bv;
  }

  f32x4 a00 = {}, a01 = {}, a11 = {};
  #pragma unroll
  for (int k0 = 0; k0 < 4; ++k0) {
    bf16x8 fr0 = *(const bf16x8*)&st[w][(lane & 15)][k0 * 32 + (lane >> 4) * 8];
    bf16x8 fr1 = *(const bf16x8*)&st[w][16 + (lane & 15)][k0 * 32 + (lane >> 4) * 8];
    a00 = __builtin_amdgcn_mfma_f32_16x16x32_bf16(fr0, fr0, a00, 0, 0, 0);
    a01 = __builtin_amdgcn_mfma_f32_16x16x32_bf16(fr0, fr1, a01, 0, 0, 0);
    a11 = __builtin_amdgcn_mfma_f32_16x16x32_bf16(fr1, fr1, a11, 0, 0, 0);
  }

  __bf16* op = top_in + (size_t)s * 512;
  ((unsigned*)op)[lane] = *(const unsigned*)&st[w][0][lane * 2];

  __bf16* sc = &st[w][0][0];
  if (lane < 6) sc[378 + lane] = f2bf(0.f);
  const int jc = lane & 15, rb = (lane >> 4) * 4;
  #pragma unroll
  for (int r = 0; r < 4; ++r) {
    {
      int i = rb + r, j = jc;
      if (i <= j) sc[i * 27 - i * (i - 1) / 2 + (j - i)] = f2bf(a00[r]);
    }
    {
      int i = rb + r, j = 16 + jc;
      if (j <= 26) sc[i * 27 - i * (i - 1) / 2 + (j - i)] = f2bf(a01[r]);
    }
    {
      int i = 16 + rb + r, j = 16 + jc;
      if (i <= j && j <= 26) sc[i * 27 - i * (i - 1) / 2 + (j - i)] = f2bf(a11[r]);
    }
  }
  asm volatile("s_waitcnt lgkmcnt(0)" ::: "memory");
  __builtin_amdgcn_sched_barrier(0);
  const unsigned* scd = (const unsigned*)sc;
  #pragma unroll
  for (int k = 0; k < 3; ++k)
    ((unsigned*)op)[64 + k * 64 + lane] = scd[k * 64 + lane];
}

// ---------------- 256x256 phase-interleaved GEMM (T1+T2+T3+T4+T5), BK=32 ----------------
// Verified R4-R6. 512 threads, 8 waves (2M x 4N), wave tile 128x64, acc[8][4]. LDS 64KB.
__global__ __launch_bounds__(512, 2) void gemm_8ph(
    const __bf16* __restrict__ A, const __bf16* __restrict__ WT,
    const float* __restrict__ bias, __bf16* __restrict__ C,
    int N, int sA, int K, int gm)
{
  __shared__ __align__(16) char smem[65536];
  const int tid = threadIdx.x, lane = tid & 63, w = tid >> 6;
  const int wm = w >> 2, wn = w & 3;

  int nb = gridDim.x;
  int id = blockIdx.x;
  int swz = ((nb & 7) == 0) ? ((id & 7) * (nb >> 3) + (id >> 3)) : id;
  const int m0 = (swz % gm) * 256, n0 = (swz / gm) * 256;

  unsigned Ld[2]; const __bf16* sAp[2]; const __bf16* sBp[2];
  #pragma unroll
  for (int h = 0; h < 2; ++h) {
    unsigned L = h * 8192u + (unsigned)w * 1024u + (unsigned)lane * 16u;
    unsigned Ls = swz16(L);
    Ld[h] = L;
    int srow = Ls >> 6, scb = Ls & 63;
    sAp[h] = A  + (size_t)(m0 + srow) * sA + (scb >> 1);
    sBp[h] = WT + (size_t)(n0 + srow) * K  + (scb >> 1);
  }

  #define STAGE_A(kt, p) { GLDS16(sAp[0] + (kt)*32, smem + (p)*32768 + Ld[0]); \
                           GLDS16(sAp[1] + (kt)*32, smem + (p)*32768 + Ld[1]); }
  #define STAGE_B(kt, p) { GLDS16(sBp[0] + (kt)*32, smem + (p)*32768 + 16384 + Ld[0]); \
                           GLDS16(sBp[1] + (kt)*32, smem + (p)*32768 + 16384 + Ld[1]); }

  const unsigned cg = (lane >> 4) * 16u;
  const unsigned rA = (lane & 15);

  f32x4 acc[8][4] = {};
  const int iters = (K >> 5) >> 1;

  STAGE_B(0, 0); STAGE_A(0, 0); STAGE_B(1, 1);
  asm volatile("s_waitcnt vmcnt(2)" ::: "memory");
  __builtin_amdgcn_s_barrier();
  __builtin_amdgcn_sched_barrier(0);

  for (int i = 0; i < iters; ++i) {
    const int t = 2 * i;
    const bool more = (i + 1 < iters);

    bf16x8 a0[4], b0[4];
    #pragma unroll
    for (int m = 0; m < 4; ++m) a0[m] = lds_frag(smem, 0, wm * 128 + m * 16 + rA, cg);
    #pragma unroll
    for (int n = 0; n < 4; ++n) b0[n] = lds_frag(smem, 16384, wn * 64 + n * 16 + rA, cg);
    STAGE_A(t + 1, 1);
    __builtin_amdgcn_s_barrier();
    asm volatile("s_waitcnt lgkmcnt(0)" ::: "memory");
    __builtin_amdgcn_sched_barrier(0);
    __builtin_amdgcn_s_setprio(1);
    #pragma unroll
    for (int m = 0; m < 4; ++m)
      #pragma unroll
      for (int n = 0; n < 4; ++n)
        acc[m][n] = __builtin_amdgcn_mfma_f32_16x16x32_bf16(a0[m], b0[n], acc[m][n], 0, 0, 0);
    __builtin_amdgcn_s_setprio(0);
    __builtin_amdgcn_s_barrier();
    __builtin_amdgcn_sched_barrier(0);

    bf16x8 a1[4];
    #pragma unroll
    for (int m = 0; m < 4; ++m) a1[m] = lds_frag(smem, 0, wm * 128 + 64 + m * 16 + rA, cg);
    if (more) STAGE_B(t + 2, 0);
    __builtin_amdgcn_s_barrier();
    asm volatile("s_waitcnt lgkmcnt(0)" ::: "memory");
    __builtin_amdgcn_sched_barrier(0);
    __builtin_amdgcn_s_setprio(1);
    #pragma unroll
    for (int m = 0; m < 4; ++m)
      #pragma unroll
      for (int n = 0; n < 4; ++n)
        acc[4 + m][n] = __builtin_amdgcn_mfma_f32_16x16x32_bf16(a1[m], b0[n], acc[4 + m][n], 0, 0, 0);
    __builtin_amdgcn_s_setprio(0);
    if (more) { asm volatile("s_waitcnt vmcnt(2)" ::: "memory"); }
    else      { asm volatile("s_waitcnt vmcnt(0)" ::: "memory"); }
    __builtin_amdgcn_s_barrier();
    __builtin_amdgcn_sched_barrier(0);

    bf16x8 a2[4], b2[4];
    #pragma unroll
    for (int m = 0; m < 4; ++m) a2[m] = lds_frag(smem, 32768, wm * 128 + m * 16 + rA, cg);
    #pragma unroll
    for (int n = 0; n < 4; ++n) b2[n] = lds_frag(smem, 32768 + 16384, wn * 64 + n * 16 + rA, cg);
    if (more) STAGE_A(t + 2, 0);
    __builtin_amdgcn_s_barrier();
    asm volatile("s_waitcnt lgkmcnt(0)" ::: "memory");
    __builtin_amdgcn_sched_barrier(0);
    __builtin_amdgcn_s_setprio(1);
    #pragma unroll
    for (int m = 0; m < 4; ++m)
      #pragma unroll
      for (int n = 0; n < 4; ++n)
        acc[m][n] = __builtin_amdgcn_mfma_f32_16x16x32_bf16(a2[m], b2[n], acc[m][n], 0, 0, 0);
    __builtin_amdgcn_s_setprio(0);
    __builtin_amdgcn_s_barrier();
    __builtin_amdgcn_sched_barrier(0);

    bf16x8 a3[4];
    #pragma unroll
    for (int m = 0; m < 4; ++m) a3[m] = lds_frag(smem, 32768, wm * 128 + 64 + m * 16 + rA, cg);
    if (more) STAGE_B(t + 3, 1);
    __builtin_amdgcn_s_barrier();
    asm volatile("s_waitcnt lgkmcnt(0)" ::: "memory");
    __builtin_amdgcn_sched_barrier(0);
    __builtin_amdgcn_s_setprio(1);
    #pragma unroll
    for (int m = 0; m < 4; ++m)
      #pragma unroll
      for (int n = 0; n < 4; ++n)
        acc[4 + m][n] = __builtin_amdgcn_mfma_f32_16x16x32_bf16(a3[m], b2[n], acc[4 + m][n], 0, 0, 0);
    __builtin_amdgcn_s_setprio(0);
    if (more) { asm volatile("s_waitcnt vmcnt(2)" ::: "memory"); }
    __builtin_amdgcn_s_barrier();
    __builtin_amdgcn_sched_barrier(0);
  }

  #pragma unroll
  for (int n = 0; n < 4; ++n) {
    int col = n0 + wn * 64 + n * 16 + (lane & 15);
    float bv = bias[col];
    #pragma unroll
    for (int m = 0; m < 8; ++m) {
      #pragma unroll
      for (int r = 0; r < 4; ++r) {
        int row = m0 + wm * 128 + m * 16 + (lane >> 4) * 4 + r;
        float v = fmaxf(acc[m][n][r] + bv, 0.f);
        C[(size_t)row * N + col] = f2bf(v);
      }
    }
  }
  #undef STAGE_A
  #undef STAGE_B
}

// ---------------- 256x128-tile phase-interleaved GEMM (t2) ----------------
__global__ __launch_bounds__(512, 2) void gemm_8ph_n128(
    const __bf16* __restrict__ A, const __bf16* __restrict__ WT,
    const float* __restrict__ bias, __bf16* __restrict__ C,
    int N, int sA, int K, int gm)
{
  __shared__ __align__(16) char smem[49152];
  const int tid = threadIdx.x, lane = tid & 63, w = tid >> 6;
  const int wm = w >> 1, wn = w & 1;

  int nb = gridDim.x;
  int id = blockIdx.x;
  int swz = ((nb & 7) == 0) ? ((id & 7) * (nb >> 3) + (id >> 3)) : id;
  const int m0 = (swz % gm) * 256, n0 = (swz / gm) * 128;

  unsigned Ld[2]; const __bf16* sAp[2]; const __bf16* sBp0;
  #pragma unroll
  for (int h = 0; h < 2; ++h) {
    unsigned L = h * 8192u + (unsigned)w * 1024u + (unsigned)lane * 16u;
    unsigned Ls = swz16(L);
    Ld[h] = L;
    int srow = Ls >> 6, scb = Ls & 63;
    sAp[h] = A + (size_t)(m0 + srow) * sA + (scb >> 1);
  }
  {
    unsigned L = (unsigned)w * 1024u + (unsigned)lane * 16u;
    unsigned Ls = swz16(L);
    int srow = Ls >> 6, scb = Ls & 63;
    sBp0 = WT + (size_t)(n0 + srow) * K + (scb >> 1);
  }

  #define STAGE_A2(kt, p) { GLDS16(sAp[0] + (kt)*32, smem + (p)*24576 + Ld[0]); \
                            GLDS16(sAp[1] + (kt)*32, smem + (p)*24576 + Ld[1]); }
  #define STAGE_B1(kt, p) { GLDS16(sBp0 + (kt)*32, smem + (p)*24576 + 16384 + Ld[0]); }

  const unsigned cg = (lane >> 4) * 16u;
  const unsigned rA = (lane & 15);

  f32x4 acc[4][4] = {};
  const int iters = (K >> 5) >> 1;

  STAGE_B1(0, 0); STAGE_A2(0, 0); STAGE_B1(1, 1);
  asm volatile("s_waitcnt vmcnt(1)" ::: "memory");
  __builtin_amdgcn_s_barrier();
  __builtin_amdgcn_sched_barrier(0);

  for (int i = 0; i < iters; ++i) {
    const int t = 2 * i;
    const bool more = (i + 1 < iters);

    bf16x8 a0[2], b0[4];
    #pragma unroll
    for (int m = 0; m < 2; ++m) a0[m] = lds_frag(smem, 0, wm * 64 + m * 16 + rA, cg);
    #pragma unroll
    for (int n = 0; n < 4; ++n) b0[n] = lds_frag(smem, 16384, wn * 64 + n * 16 + rA, cg);
    STAGE_A2(t + 1, 1);
    __builtin_amdgcn_s_barrier();
    asm volatile("s_waitcnt lgkmcnt(0)" ::: "memory");
    __builtin_amdgcn_sched_barrier(0);
    __builtin_amdgcn_s_setprio(1);
    #pragma unroll
    for (int m = 0; m < 2; ++m)
      #pragma unroll
      for (int n = 0; n < 4; ++n)
        acc[m][n] = __builtin_amdgcn_mfma_f32_16x16x32_bf16(a0[m], b0[n], acc[m][n], 0, 0, 0);
    __builtin_amdgcn_s_setprio(0);
    __builtin_amdgcn_s_barrier();
    __builtin_amdgcn_sched_barrier(0);

    bf16x8 a1[2];
    #pragma unroll
    for (int m = 0; m < 2; ++m) a1[m] = lds_frag(smem, 0, wm * 64 + 32 + m * 16 + rA, cg);
    if (more) STAGE_B1(t + 2, 0);
    __builtin_amdgcn_s_barrier();
    asm volatile("s_waitcnt lgkmcnt(0)" ::: "memory");
    __builtin_amdgcn_sched_barrier(0);
    __builtin_amdgcn_s_setprio(1);
    #pragma unroll
    for (int m = 0; m < 2; ++m)
      #pragma unroll
      for (int n = 0; n < 4; ++n)
        acc[2 + m][n] = __builtin_amdgcn_mfma_f32_16x16x32_bf16(a1[m], b0[n], acc[2 + m][n], 0, 0, 0);
    __builtin_amdgcn_s_setprio(0);
    if (more) { asm volatile("s_waitcnt vmcnt(1)" ::: "memory"); }
    else      { asm volatile("s_waitcnt vmcnt(0)" ::: "memory"); }
    __builtin_amdgcn_s_barrier();
    __builtin_amdgcn_sched_barrier(0);

    bf16x8 a2[2], b2[4];
    #pragma unroll
    for (int m = 0; m < 2; ++m) a2[m] = lds_frag(smem, 24576, wm * 64 + m * 16 + rA, cg);
    #pragma unroll
    for (int n = 0; n < 4; ++n) b2[n] = lds_frag(smem, 24576 + 16384, wn * 64 + n * 16 + rA, cg);
    if (more) STAGE_A2(t + 2, 0);
    __builtin_amdgcn_s_barrier();
    asm volatile("s_waitcnt lgkmcnt(0)" ::: "memory");
    __builtin_amdgcn_sched_barrier(0);
    __builtin_amdgcn_s_setprio(1);
    #pragma unroll
    for (int m = 0; m < 2; ++m)
      #pragma unroll
      for (int n = 0; n < 4; ++n)
        acc[m][n] = __builtin_amdgcn_mfma_f32_16x16x32_bf16(a2[m], b2[n], acc[m][n], 0, 0, 0);
    __builtin_amdgcn_s_setprio(0);
    __builtin_amdgcn_s_barrier();
    __builtin_amdgcn_sched_barrier(0);

    bf16x8 a3[2];
    #pragma unroll
    for (int m = 0; m < 2; ++m) a3[m] = lds_frag(smem, 24576, wm * 64 + 32 + m * 16 + rA, cg);
    if (more) STAGE_B1(t + 3, 1);
    __builtin_amdgcn_s_barrier();
    asm volatile("s_waitcnt lgkmcnt(0)" ::: "memory");
    __builtin_amdgcn_sched_barrier(0);
    __builtin_amdgcn_s_setprio(1);
    #pragma unroll
    for (int m = 0; m < 2; ++m)
      #pragma unroll
      for (int n = 0; n < 4; ++n)
        acc[2 + m][n] = __builtin_amdgcn_mfma_f32_16x16x32_bf16(a3[m], b2[n], acc[2 + m][n], 0, 0, 0);
    __builtin_amdgcn_s_setprio(0);
    if (more) { asm volatile("s_waitcnt vmcnt(1)" ::: "memory"); }
    __builtin_amdgcn_s_barrier();
    __builtin_amdgcn_sched_barrier(0);
  }

  #pragma unroll
  for (int n = 0; n < 4; ++n) {
    int col = n0 + wn * 64 + n * 16 + (lane & 15);
    float bv = bias[col];
    #pragma unroll
    for (int m = 0; m < 4; ++m) {
      #pragma unroll
      for (int r = 0; r < 4; ++r) {
        int row = m0 + wm * 64 + m * 16 + (lane >> 4) * 4 + r;
        float v = fmaxf(acc[m][n][r] + bv, 0.f);
        C[(size_t)row * N + col] = f2bf(v);
      }
    }
  }
  #undef STAGE_A2
  #undef STAGE_B1
}

// ---------------- fused t3 GEMM (64x256 tile, N=256 K=512) + final dot ----------------
__global__ __launch_bounds__(256) void gemm_t3_final(
    const __bf16* __restrict__ A, const __bf16* __restrict__ WT,
    const float* __restrict__ b3, const float* __restrict__ w4,
    const float* __restrict__ b4, float* __restrict__ out)
{
  __shared__ __bf16 As[64][32];
  __shared__ __bf16 Bs[256][32];
  __shared__ float red[64][4];
  const int tid = threadIdx.x, lane = tid & 63, wid = tid >> 6;
  const int m0 = blockIdx.x * 64;
  const int srow = wid * 16 + (lane >> 2);
  const int scol = (lane & 3) * 8;
  const __bf16* Ag0 = A + (size_t)(m0 + srow) * 512 + scol;

  f32x4 acc[4][4] = {};

  for (int k0 = 0; k0 < 512; k0 += 32) {
    __syncthreads();
    GLDS16(Ag0 + k0, &As[srow][scol]);
    #pragma unroll
    for (int c = 0; c < 4; ++c) {
      int br = wid * 64 + c * 16 + (lane >> 2);
      GLDS16(WT + (size_t)br * 512 + k0 + scol, &Bs[br][scol]);
    }
    __syncthreads();

    bf16x8 af[4], bfv[4];
    #pragma unroll
    for (int m = 0; m < 4; ++m)
      af[m] = *(const bf16x8*)&As[m * 16 + (lane & 15)][(lane >> 4) * 8];
    #pragma unroll
    for (int n = 0; n < 4; ++n)
      bfv[n] = *(const bf16x8*)&Bs[wid * 64 + n * 16 + (lane & 15)][(lane >> 4) * 8];
    #pragma unroll
    for (int m = 0; m < 4; ++m)
      #pragma unroll
      for (int n = 0; n < 4; ++n)
        acc[m][n] = __builtin_amdgcn_mfma_f32_16x16x32_bf16(af[m], bfv[n], acc[m][n], 0, 0, 0);
  }

  float pd[4][4];
  #pragma unroll
  for (int m = 0; m < 4; ++m)
    #pragma unroll
    for (int r = 0; r < 4; ++r) pd[m][r] = 0.f;
  #pragma unroll
  for (int n = 0; n < 4; ++n) {
    int col = wid * 64 + n * 16 + (lane & 15);
    float bb = b3[col];
    float wc = w4[col];
    #pragma unroll
    for (int m = 0; m < 4; ++m)
      #pragma unroll
      for (int r = 0; r < 4; ++r)
        pd[m][r] += fmaxf(acc[m][n][r] + bb, 0.f) * wc;
  }
  #pragma unroll
  for (int m = 0; m < 4; ++m)
    #pragma unroll
    for (int r = 0; r < 4; ++r) {
      float s = pd[m][r];
      s += __shfl_xor(s, 1); s += __shfl_xor(s, 2);
      s += __shfl_xor(s, 4); s += __shfl_xor(s, 8);
      if ((lane & 15) == 0) red[m * 16 + (lane >> 4) * 4 + r][wid] = s;
    }
  __syncthreads();
  if (tid < 64)
    out[m0 + tid] = red[tid][0] + red[tid][1] + red[tid][2] + red[tid][3] + b4[0];
}

extern "C" void kernel_launch(void* const* d_in, const int* in_sizes, int n_in,
                              void* d_out, int out_size, void* d_ws, size_t ws_size,
                              hipStream_t stream)
{
  const float* x_dense = (const float*)d_in[0];
  const int*   x_cat   = (const int*)d_in[1];
  const float* emb     = (const float*)d_in[2];
  const float* wb[3] = {(const float*)d_in[3], (const float*)d_in[5], (const float*)d_in[7]};
  const float* bb[3] = {(const float*)d_in[4], (const float*)d_in[6], (const float*)d_in[8]};
  const float* wt[5] = {(const float*)d_in[9],  (const float*)d_in[11], (const float*)d_in[13],
                        (const float*)d_in[15], (const float*)d_in[17]};
  const float* bt[5] = {(const float*)d_in[10], (const float*)d_in[12], (const float*)d_in[14],
                        (const float*)d_in[16], (const float*)d_in[18]};
  float* out = (float*)d_out;

  char* ws = (char*)d_ws;
  const size_t MB = 1ull << 20;
  __bf16* wt_b0 = (__bf16*)(ws + 0 * MB);   // 512x32
  __bf16* wt_b1 = (__bf16*)(ws + 1 * MB);   // 256x512
  __bf16* wt_b2 = (__bf16*)(ws + 2 * MB);   // 128x256
  __bf16* wt_t0 = (__bf16*)(ws + 3 * MB);   // 1024x512
  __bf16* wt_t1 = (__bf16*)(ws + 4 * MB);   // 1024x1024
  __bf16* wt_t2 = (__bf16*)(ws + 6 * MB);   // 512x1024
  __bf16* wt_t3 = (__bf16*)(ws + 7 * MB);   // 256x512
  __bf16* h2     = (__bf16*)(ws + 8 * MB);   // 16384x128 = 4MB
  __bf16* top_in = (__bf16*)(ws + 12 * MB);  // 16MB (region C)
  __bf16* t2     = (__bf16*)(ws + 12 * MB);  // (region C, after top_in dead)
  __bf16* t1     = (__bf16*)(ws + 28 * MB);  // 32MB (region A)
  __bf16* t0     = (__bf16*)(ws + 60 * MB);  // 32MB (region B)

  // ---- fused weight prep (1 dispatch) ----
  TJobs js;
  const float* Ws[7] = {wb[0], wb[1], wb[2], wt[0], wt[1], wt[2], wt[3]};
  __bf16* WTs[7] = {wt_b0, wt_b1, wt_b2, wt_t0, wt_t1, wt_t2, wt_t3};
  int Ks[7]  = {13, 512, 256, 506, 1024, 1024, 512};
  int Ns[7]  = {512, 256, 128, 1024, 1024, 512, 256};
  int Kps[7] = {32, 512, 256, 512, 1024, 1024, 512};
  int off = 0;
  for (int i = 0; i < 7; ++i) {
    int tx = (Kps[i] + 63) / 64, ty = (Ns[i] + 63) / 64;
    js.j[i] = TJob{Ws[i], WTs[i], Ks[i], Ns[i], Kps[i], tx, off};
    off += tx * ty;
  }
  transpose_all<<<dim3(off), dim3(256), 0, stream>>>(js, 7);

  // ---- fused bottom MLP ----
  bottom_fused<<<dim3(BATCH / 32), dim3(256), 0, stream>>>(
      x_dense, wt_b0, bb[0], wt_b1, bb[1], wt_b2, bb[2], h2);

  // ---- embedding + interaction ----
  interact_mfma<<<dim3(BATCH / 4), dim3(256), 0, stream>>>(h2, x_cat, emb, top_in);

  // ---- top MLP: t0,t1 on 256^2 gemm_8ph (A/B vs bm128) ----
  gemm_8ph<<<dim3(256), dim3(512), 0, stream>>>(top_in, wt_t0, bt[0], t0, 1024, 512, 512, 64);
  gemm_8ph<<<dim3(256), dim3(512), 0, stream>>>(t0, wt_t1, bt[1], t1, 1024, 1024, 1024, 64);
  gemm_8ph_n128<<<dim3(256), dim3(512), 0, stream>>>(t1, wt_t2, bt[2], t2, 512, 1024, 1024, 64);

  // ---- fused t3 + final ----
  gemm_t3_final<<<dim3(256), dim3(256), 0, stream>>>(t2, wt_t3, bt[3], wt[4], bt[4], out);
}

// Round 12
// 188.314 us; speedup vs baseline: 1.0650x; 1.0650x over previous
//
#include <hip/hip_runtime.h>
#include <cstdint>
#include <cstddef>

#define BATCH 16384
#define VOCAB_MASK (4194304 - 1)

typedef __attribute__((ext_vector_type(4))) float f32x4;
typedef __attribute__((ext_vector_type(8))) __bf16 bf16x8;
typedef __attribute__((ext_vector_type(4))) __bf16 bf16x4;

static_assert(sizeof(bf16x8) == 16, "bf16x8 must be 16 bytes");

static __device__ __forceinline__ __bf16 f2bf(float f) {
  union { float f; unsigned u; } in; in.f = f;
  unsigned r = in.u + 0x7FFF + ((in.u >> 16) & 1);
  union { unsigned short s; __bf16 b; } out; out.s = (unsigned short)(r >> 16);
  return out.b;
}
static __device__ __forceinline__ float bf2f(__bf16 b) {
  union { __bf16 b; unsigned short s; } in; in.b = b;
  union { unsigned u; float f; } out; out.u = ((unsigned)in.s) << 16;
  return out.f;
}

// async global->LDS, 16B per lane. LDS dest must be wave-uniform base + lane*16.
#define GLDS16(g, l) __builtin_amdgcn_global_load_lds( \
    (const __attribute__((address_space(1))) unsigned int*)(g), \
    (__attribute__((address_space(3))) unsigned int*)(l), 16, 0, 0)

// swizzle: XOR 16B-chunk index bits (involution)
static __device__ __forceinline__ unsigned swz16(unsigned b) {
  return b ^ ((((b >> 6) & 3u) ^ ((b >> 8) & 3u)) << 4);
}
static __device__ __forceinline__ bf16x8 lds_frag(const char* smem, unsigned base,
                                                  unsigned r, unsigned cg) {
  unsigned b = r * 64u + cg;
  return *(const bf16x8*)(smem + base + swz16(b));
}

// ---------------- fused weight transpose + bf16 convert: WT[n][k] = W[k][n] ----------------
struct TJob { const float* W; __bf16* WT; int K, N, Kp, tx, off; };
struct TJobs { TJob j[7]; };

__global__ __launch_bounds__(256) void transpose_all(TJobs js, int njobs)
{
  __shared__ float tile[64][65];
  int b = blockIdx.x;
  int ji = 0;
  #pragma unroll
  for (int i = 1; i < 7; ++i) if (i < njobs && b >= js.j[i].off) ji = i;
  const TJob jb = js.j[ji];
  int lb = b - jb.off;
  int bx = lb % jb.tx, by = lb / jb.tx;
  const int kb = bx * 64, nb = by * 64;
  const int tx = threadIdx.x & 63, ty = threadIdx.x >> 6;
  #pragma unroll
  for (int i = 0; i < 64; i += 4) {
    int k = kb + ty + i, n = nb + tx;
    tile[ty + i][tx] = (k < jb.K && n < jb.N) ? jb.W[(size_t)k * jb.N + n] : 0.f;
  }
  __syncthreads();
  #pragma unroll
  for (int i = 0; i < 64; i += 4) {
    int n = nb + ty + i, k = kb + tx;
    if (n < jb.N && k < jb.Kp) jb.WT[(size_t)n * jb.Kp + k] = f2bf(tile[tx][ty + i]);
  }
}

// ---------------- fused bottom MLP: x(13) -> 512 -> 256 -> 128 ----------------
__global__ __launch_bounds__(256) void bottom_fused(
    const float* __restrict__ x,
    const __bf16* __restrict__ w0t, const float* __restrict__ b0,
    const __bf16* __restrict__ w1t, const float* __restrict__ b1,
    const __bf16* __restrict__ w2t, const float* __restrict__ b2,
    __bf16* __restrict__ h2out)
{
  __shared__ __bf16 h0s[32][520];
  __shared__ __bf16 h1s[32][264];
  __shared__ __bf16 As[32][40];
  const int tid = threadIdx.x, lane = tid & 63, w = tid >> 6;
  const int r0 = blockIdx.x * 32;
  const unsigned rA = lane & 15, cgw = (lane >> 4) * 8;

  for (int idx = tid; idx < 32 * 40; idx += 256) {
    int row = idx / 40, k = idx - row * 40;
    float v = (k < 13) ? x[(size_t)(r0 + row) * 13 + k] : 0.f;
    As[row][k] = f2bf(v);
  }
  __syncthreads();

  bf16x8 a00 = *(const bf16x8*)&As[rA][cgw];
  bf16x8 a01 = *(const bf16x8*)&As[rA + 16][cgw];
  #pragma unroll
  for (int p = 0; p < 2; ++p) {
    bf16x8 bv[4];
    #pragma unroll
    for (int n = 0; n < 4; ++n)
      bv[n] = *(const bf16x8*)(w0t + (size_t)(p * 256 + w * 64 + n * 16 + rA) * 32 + cgw);
    f32x4 acc[2][4] = {};
    #pragma unroll
    for (int n = 0; n < 4; ++n) {
      acc[0][n] = __builtin_amdgcn_mfma_f32_16x16x32_bf16(a00, bv[n], acc[0][n], 0, 0, 0);
      acc[1][n] = __builtin_amdgcn_mfma_f32_16x16x32_bf16(a01, bv[n], acc[1][n], 0, 0, 0);
    }
    #pragma unroll
    for (int m = 0; m < 2; ++m)
      #pragma unroll
      for (int n = 0; n < 4; ++n) {
        int col = p * 256 + w * 64 + n * 16 + (int)rA;
        float bb = b0[col];
        #pragma unroll
        for (int r = 0; r < 4; ++r) {
          int row = m * 16 + (lane >> 4) * 4 + r;
          h0s[row][col] = f2bf(fmaxf(acc[m][n][r] + bb, 0.f));
        }
      }
  }
  __syncthreads();

  f32x4 acc1[2][4] = {};
  const __bf16* w1p = w1t + (size_t)(w * 64 + rA) * 512 + cgw;
  bf16x8 c0 = *(const bf16x8*)(w1p + 0 * 8192);
  bf16x8 c1 = *(const bf16x8*)(w1p + 1 * 8192);
  bf16x8 c2 = *(const bf16x8*)(w1p + 2 * 8192);
  bf16x8 c3 = *(const bf16x8*)(w1p + 3 * 8192);
  for (int k0 = 0; k0 < 512; k0 += 32) {
    bf16x8 n0v, n1v, n2v, n3v;
    const bool more = (k0 + 32 < 512);
    if (more) {
      n0v = *(const bf16x8*)(w1p + 0 * 8192 + k0 + 32);
      n1v = *(const bf16x8*)(w1p + 1 * 8192 + k0 + 32);
      n2v = *(const bf16x8*)(w1p + 2 * 8192 + k0 + 32);
      n3v = *(const bf16x8*)(w1p + 3 * 8192 + k0 + 32);
    }
    bf16x8 av0 = *(const bf16x8*)&h0s[rA][k0 + cgw];
    bf16x8 av1 = *(const bf16x8*)&h0s[rA + 16][k0 + cgw];
    acc1[0][0] = __builtin_amdgcn_mfma_f32_16x16x32_bf16(av0, c0, acc1[0][0], 0, 0, 0);
    acc1[1][0] = __builtin_amdgcn_mfma_f32_16x16x32_bf16(av1, c0, acc1[1][0], 0, 0, 0);
    acc1[0][1] = __builtin_amdgcn_mfma_f32_16x16x32_bf16(av0, c1, acc1[0][1], 0, 0, 0);
    acc1[1][1] = __builtin_amdgcn_mfma_f32_16x16x32_bf16(av1, c1, acc1[1][1], 0, 0, 0);
    acc1[0][2] = __builtin_amdgcn_mfma_f32_16x16x32_bf16(av0, c2, acc1[0][2], 0, 0, 0);
    acc1[1][2] = __builtin_amdgcn_mfma_f32_16x16x32_bf16(av1, c2, acc1[1][2], 0, 0, 0);
    acc1[0][3] = __builtin_amdgcn_mfma_f32_16x16x32_bf16(av0, c3, acc1[0][3], 0, 0, 0);
    acc1[1][3] = __builtin_amdgcn_mfma_f32_16x16x32_bf16(av1, c3, acc1[1][3], 0, 0, 0);
    if (more) { c0 = n0v; c1 = n1v; c2 = n2v; c3 = n3v; }
  }
  #pragma unroll
  for (int m = 0; m < 2; ++m)
    #pragma unroll
    for (int n = 0; n < 4; ++n) {
      int col = w * 64 + n * 16 + (int)rA;
      float bb = b1[col];
      #pragma unroll
      for (int r = 0; r < 4; ++r) {
        int row = m * 16 + (lane >> 4) * 4 + r;
        h1s[row][col] = f2bf(fmaxf(acc1[m][n][r] + bb, 0.f));
      }
    }
  __syncthreads();

  f32x4 acc2[2][2] = {};
  const __bf16* w2p = w2t + (size_t)(w * 32 + rA) * 256 + cgw;
  bf16x8 d0 = *(const bf16x8*)(w2p + 0);
  bf16x8 d1 = *(const bf16x8*)(w2p + 4096);
  for (int k0 = 0; k0 < 256; k0 += 32) {
    bf16x8 e0, e1;
    const bool more = (k0 + 32 < 256);
    if (more) {
      e0 = *(const bf16x8*)(w2p + k0 + 32);
      e1 = *(const bf16x8*)(w2p + 4096 + k0 + 32);
    }
    bf16x8 av0 = *(const bf16x8*)&h1s[rA][k0 + cgw];
    bf16x8 av1 = *(const bf16x8*)&h1s[rA + 16][k0 + cgw];
    acc2[0][0] = __builtin_amdgcn_mfma_f32_16x16x32_bf16(av0, d0, acc2[0][0], 0, 0, 0);
    acc2[1][0] = __builtin_amdgcn_mfma_f32_16x16x32_bf16(av1, d0, acc2[1][0], 0, 0, 0);
    acc2[0][1] = __builtin_amdgcn_mfma_f32_16x16x32_bf16(av0, d1, acc2[0][1], 0, 0, 0);
    acc2[1][1] = __builtin_amdgcn_mfma_f32_16x16x32_bf16(av1, d1, acc2[1][1], 0, 0, 0);
    if (more) { d0 = e0; d1 = e1; }
  }
  #pragma unroll
  for (int m = 0; m < 2; ++m)
    #pragma unroll
    for (int n = 0; n < 2; ++n) {
      int col = w * 32 + n * 16 + (int)rA;
      float bb = b2[col];
      #pragma unroll
      for (int r = 0; r < 4; ++r) {
        int row = m * 16 + (lane >> 4) * 4 + r;
        h2out[(size_t)(r0 + row) * 128 + col] = f2bf(fmaxf(acc2[m][n][r] + bb, 0.f));
      }
    }
}

// ---------------- embedding gather (float4) + MFMA interaction, coalesced stores ----------
__global__ __launch_bounds__(256) void interact_mfma(
    const __bf16* __restrict__ bot, const int* __restrict__ xcat,
    const float* __restrict__ emb, __bf16* __restrict__ top_in)
{
  __shared__ __bf16 st[4][32][136];
  const int tid = threadIdx.x, lane = tid & 63, w = tid >> 6;
  const int s = blockIdx.x * 4 + w;

  const int* xr = xcat + (size_t)s * 26;
  float4 buf[13];
  #pragma unroll
  for (int i = 0; i < 13; ++i) {
    int fi = 2 * i + (lane >> 5);
    int ridx = xr[fi] & VOCAB_MASK;
    buf[i] = *(const float4*)(emb + (size_t)ridx * 128 + (lane & 31) * 4);
  }

  *(unsigned*)&st[w][0][lane * 2] = *(const unsigned*)(bot + (size_t)s * 128 + lane * 2);
  #pragma unroll
  for (int r = 27; r < 32; ++r) *(unsigned*)&st[w][r][lane * 2] = 0u;
  #pragma unroll
  for (int i = 0; i < 13; ++i) {
    int row = 1 + 2 * i + (lane >> 5);
    bf16x4 bv;
    bv[0] = f2bf(buf[i].x); bv[1] = f2bf(buf[i].y);
    bv[2] = f2bf(buf[i].z); bv[3] = f2bf(buf[i].w);
    *(bf16x4*)&st[w][row][(lane & 31) * 4] = bv;
  }

  f32x4 a00 = {}, a01 = {}, a11 = {};
  #pragma unroll
  for (int k0 = 0; k0 < 4; ++k0) {
    bf16x8 fr0 = *(const bf16x8*)&st[w][(lane & 15)][k0 * 32 + (lane >> 4) * 8];
    bf16x8 fr1 = *(const bf16x8*)&st[w][16 + (lane & 15)][k0 * 32 + (lane >> 4) * 8];
    a00 = __builtin_amdgcn_mfma_f32_16x16x32_bf16(fr0, fr0, a00, 0, 0, 0);
    a01 = __builtin_amdgcn_mfma_f32_16x16x32_bf16(fr0, fr1, a01, 0, 0, 0);
    a11 = __builtin_amdgcn_mfma_f32_16x16x32_bf16(fr1, fr1, a11, 0, 0, 0);
  }

  __bf16* op = top_in + (size_t)s * 512;
  ((unsigned*)op)[lane] = *(const unsigned*)&st[w][0][lane * 2];

  __bf16* sc = &st[w][0][0];
  if (lane < 6) sc[378 + lane] = f2bf(0.f);
  const int jc = lane & 15, rb = (lane >> 4) * 4;
  #pragma unroll
  for (int r = 0; r < 4; ++r) {
    {
      int i = rb + r, j = jc;
      if (i <= j) sc[i * 27 - i * (i - 1) / 2 + (j - i)] = f2bf(a00[r]);
    }
    {
      int i = rb + r, j = 16 + jc;
      if (j <= 26) sc[i * 27 - i * (i - 1) / 2 + (j - i)] = f2bf(a01[r]);
    }
    {
      int i = 16 + rb + r, j = 16 + jc;
      if (i <= j && j <= 26) sc[i * 27 - i * (i - 1) / 2 + (j - i)] = f2bf(a11[r]);
    }
  }
  asm volatile("s_waitcnt lgkmcnt(0)" ::: "memory");
  __builtin_amdgcn_sched_barrier(0);
  const unsigned* scd = (const unsigned*)sc;
  #pragma unroll
  for (int k = 0; k < 3; ++k)
    ((unsigned*)op)[64 + k * 64 + lane] = scd[k * 64 + lane];
}

// ---------------- 128x256-tile phase-interleaved GEMM (2 blocks/CU), BK=32 ----------------
__global__ __launch_bounds__(512, 4) void gemm_8ph_bm128(
    const __bf16* __restrict__ A, const __bf16* __restrict__ WT,
    const float* __restrict__ bias, __bf16* __restrict__ C,
    int N, int sA, int K, int gm)
{
  __shared__ __align__(16) char smem[49152];
  const int tid = threadIdx.x, lane = tid & 63, w = tid >> 6;
  const int wm = w >> 2, wn = w & 3;

  int nb = gridDim.x;
  int id = blockIdx.x;
  int swz = ((nb & 7) == 0) ? ((id & 7) * (nb >> 3) + (id >> 3)) : id;
  const int m0 = (swz % gm) * 128, n0 = (swz / gm) * 256;

  unsigned LdA; const __bf16* sApA;
  {
    unsigned L = (unsigned)w * 1024u + (unsigned)lane * 16u;
    unsigned Ls = swz16(L);
    LdA = L;
    sApA = A + (size_t)(m0 + (Ls >> 6)) * sA + ((Ls & 63) >> 1);
  }
  unsigned LdB[2]; const __bf16* sBp[2];
  #pragma unroll
  for (int h = 0; h < 2; ++h) {
    unsigned L = h * 8192u + (unsigned)w * 1024u + (unsigned)lane * 16u;
    unsigned Ls = swz16(L);
    LdB[h] = L;
    sBp[h] = WT + (size_t)(n0 + (Ls >> 6)) * K + ((Ls & 63) >> 1);
  }

  #define STAGE_A1(kt, p) { GLDS16(sApA + (kt)*32, smem + (p)*24576 + LdA); }
  #define STAGE_B2(kt, p) { GLDS16(sBp[0] + (kt)*32, smem + (p)*24576 + 8192 + LdB[0]); \
                            GLDS16(sBp[1] + (kt)*32, smem + (p)*24576 + 8192 + LdB[1]); }

  const unsigned cg = (lane >> 4) * 16u;
  const unsigned rA = (lane & 15);

  f32x4 acc[4][4] = {};
  const int iters = (K >> 5) >> 1;

  STAGE_B2(0, 0); STAGE_A1(0, 0); STAGE_B2(1, 1);
  asm volatile("s_waitcnt vmcnt(2)" ::: "memory");
  __builtin_amdgcn_s_barrier();
  __builtin_amdgcn_sched_barrier(0);

  for (int i = 0; i < iters; ++i) {
    const int t = 2 * i;
    const bool more = (i + 1 < iters);

    bf16x8 a0[2], b0[4];
    #pragma unroll
    for (int m = 0; m < 2; ++m) a0[m] = lds_frag(smem, 0, wm * 64 + m * 16 + rA, cg);
    #pragma unroll
    for (int n = 0; n < 4; ++n) b0[n] = lds_frag(smem, 8192, wn * 64 + n * 16 + rA, cg);
    STAGE_A1(t + 1, 1);
    __builtin_amdgcn_s_barrier();
    asm volatile("s_waitcnt lgkmcnt(0)" ::: "memory");
    __builtin_amdgcn_sched_barrier(0);
    __builtin_amdgcn_s_setprio(1);
    #pragma unroll
    for (int m = 0; m < 2; ++m)
      #pragma unroll
      for (int n = 0; n < 4; ++n)
        acc[m][n] = __builtin_amdgcn_mfma_f32_16x16x32_bf16(a0[m], b0[n], acc[m][n], 0, 0, 0);
    __builtin_amdgcn_s_setprio(0);
    __builtin_amdgcn_s_barrier();
    __builtin_amdgcn_sched_barrier(0);

    bf16x8 a1[2];
    #pragma unroll
    for (int m = 0; m < 2; ++m) a1[m] = lds_frag(smem, 0, wm * 64 + 32 + m * 16 + rA, cg);
    if (more) STAGE_B2(t + 2, 0);
    __builtin_amdgcn_s_barrier();
    asm volatile("s_waitcnt lgkmcnt(0)" ::: "memory");
    __builtin_amdgcn_sched_barrier(0);
    __builtin_amdgcn_s_setprio(1);
    #pragma unroll
    for (int m = 0; m < 2; ++m)
      #pragma unroll
      for (int n = 0; n < 4; ++n)
        acc[2 + m][n] = __builtin_amdgcn_mfma_f32_16x16x32_bf16(a1[m], b0[n], acc[2 + m][n], 0, 0, 0);
    __builtin_amdgcn_s_setprio(0);
    if (more) { asm volatile("s_waitcnt vmcnt(2)" ::: "memory"); }
    else      { asm volatile("s_waitcnt vmcnt(0)" ::: "memory"); }
    __builtin_amdgcn_s_barrier();
    __builtin_amdgcn_sched_barrier(0);

    bf16x8 a2[2], b2[4];
    #pragma unroll
    for (int m = 0; m < 2; ++m) a2[m] = lds_frag(smem, 24576, wm * 64 + m * 16 + rA, cg);
    #pragma unroll
    for (int n = 0; n < 4; ++n) b2[n] = lds_frag(smem, 24576 + 8192, wn * 64 + n * 16 + rA, cg);
    if (more) STAGE_A1(t + 2, 0);
    __builtin_amdgcn_s_barrier();
    asm volatile("s_waitcnt lgkmcnt(0)" ::: "memory");
    __builtin_amdgcn_sched_barrier(0);
    __builtin_amdgcn_s_setprio(1);
    #pragma unroll
    for (int m = 0; m < 2; ++m)
      #pragma unroll
      for (int n = 0; n < 4; ++n)
        acc[m][n] = __builtin_amdgcn_mfma_f32_16x16x32_bf16(a2[m], b2[n], acc[m][n], 0, 0, 0);
    __builtin_amdgcn_s_setprio(0);
    __builtin_amdgcn_s_barrier();
    __builtin_amdgcn_sched_barrier(0);

    bf16x8 a3[2];
    #pragma unroll
    for (int m = 0; m < 2; ++m) a3[m] = lds_frag(smem, 24576, wm * 64 + 32 + m * 16 + rA, cg);
    if (more) STAGE_B2(t + 3, 1);
    __builtin_amdgcn_s_barrier();
    asm volatile("s_waitcnt lgkmcnt(0)" ::: "memory");
    __builtin_amdgcn_sched_barrier(0);
    __builtin_amdgcn_s_setprio(1);
    #pragma unroll
    for (int m = 0; m < 2; ++m)
      #pragma unroll
      for (int n = 0; n < 4; ++n)
        acc[2 + m][n] = __builtin_amdgcn_mfma_f32_16x16x32_bf16(a3[m], b2[n], acc[2 + m][n], 0, 0, 0);
    __builtin_amdgcn_s_setprio(0);
    if (more) { asm volatile("s_waitcnt vmcnt(2)" ::: "memory"); }
    __builtin_amdgcn_s_barrier();
    __builtin_amdgcn_sched_barrier(0);
  }

  #pragma unroll
  for (int n = 0; n < 4; ++n) {
    int col = n0 + wn * 64 + n * 16 + (lane & 15);
    float bv = bias[col];
    #pragma unroll
    for (int m = 0; m < 4; ++m) {
      #pragma unroll
      for (int r = 0; r < 4; ++r) {
        int row = m0 + wm * 64 + m * 16 + (lane >> 4) * 4 + r;
        float v = fmaxf(acc[m][n][r] + bv, 0.f);
        C[(size_t)row * N + col] = f2bf(v);
      }
    }
  }
  #undef STAGE_A1
  #undef STAGE_B2
}

// ---------------- 256x128-tile phase-interleaved GEMM (t2) ----------------
__global__ __launch_bounds__(512, 2) void gemm_8ph_n128(
    const __bf16* __restrict__ A, const __bf16* __restrict__ WT,
    const float* __restrict__ bias, __bf16* __restrict__ C,
    int N, int sA, int K, int gm)
{
  __shared__ __align__(16) char smem[49152];
  const int tid = threadIdx.x, lane = tid & 63, w = tid >> 6;
  const int wm = w >> 1, wn = w & 1;

  int nb = gridDim.x;
  int id = blockIdx.x;
  int swz = ((nb & 7) == 0) ? ((id & 7) * (nb >> 3) + (id >> 3)) : id;
  const int m0 = (swz % gm) * 256, n0 = (swz / gm) * 128;

  unsigned Ld[2]; const __bf16* sAp[2]; const __bf16* sBp0;
  #pragma unroll
  for (int h = 0; h < 2; ++h) {
    unsigned L = h * 8192u + (unsigned)w * 1024u + (unsigned)lane * 16u;
    unsigned Ls = swz16(L);
    Ld[h] = L;
    int srow = Ls >> 6, scb = Ls & 63;
    sAp[h] = A + (size_t)(m0 + srow) * sA + (scb >> 1);
  }
  {
    unsigned L = (unsigned)w * 1024u + (unsigned)lane * 16u;
    unsigned Ls = swz16(L);
    int srow = Ls >> 6, scb = Ls & 63;
    sBp0 = WT + (size_t)(n0 + srow) * K + (scb >> 1);
  }

  #define STAGE_A2(kt, p) { GLDS16(sAp[0] + (kt)*32, smem + (p)*24576 + Ld[0]); \
                            GLDS16(sAp[1] + (kt)*32, smem + (p)*24576 + Ld[1]); }
  #define STAGE_B1(kt, p) { GLDS16(sBp0 + (kt)*32, smem + (p)*24576 + 16384 + Ld[0]); }

  const unsigned cg = (lane >> 4) * 16u;
  const unsigned rA = (lane & 15);

  f32x4 acc[4][4] = {};
  const int iters = (K >> 5) >> 1;

  STAGE_B1(0, 0); STAGE_A2(0, 0); STAGE_B1(1, 1);
  asm volatile("s_waitcnt vmcnt(1)" ::: "memory");
  __builtin_amdgcn_s_barrier();
  __builtin_amdgcn_sched_barrier(0);

  for (int i = 0; i < iters; ++i) {
    const int t = 2 * i;
    const bool more = (i + 1 < iters);

    bf16x8 a0[2], b0[4];
    #pragma unroll
    for (int m = 0; m < 2; ++m) a0[m] = lds_frag(smem, 0, wm * 64 + m * 16 + rA, cg);
    #pragma unroll
    for (int n = 0; n < 4; ++n) b0[n] = lds_frag(smem, 16384, wn * 64 + n * 16 + rA, cg);
    STAGE_A2(t + 1, 1);
    __builtin_amdgcn_s_barrier();
    asm volatile("s_waitcnt lgkmcnt(0)" ::: "memory");
    __builtin_amdgcn_sched_barrier(0);
    __builtin_amdgcn_s_setprio(1);
    #pragma unroll
    for (int m = 0; m < 2; ++m)
      #pragma unroll
      for (int n = 0; n < 4; ++n)
        acc[m][n] = __builtin_amdgcn_mfma_f32_16x16x32_bf16(a0[m], b0[n], acc[m][n], 0, 0, 0);
    __builtin_amdgcn_s_setprio(0);
    __builtin_amdgcn_s_barrier();
    __builtin_amdgcn_sched_barrier(0);

    bf16x8 a1[2];
    #pragma unroll
    for (int m = 0; m < 2; ++m) a1[m] = lds_frag(smem, 0, wm * 64 + 32 + m * 16 + rA, cg);
    if (more) STAGE_B1(t + 2, 0);
    __builtin_amdgcn_s_barrier();
    asm volatile("s_waitcnt lgkmcnt(0)" ::: "memory");
    __builtin_amdgcn_sched_barrier(0);
    __builtin_amdgcn_s_setprio(1);
    #pragma unroll
    for (int m = 0; m < 2; ++m)
      #pragma unroll
      for (int n = 0; n < 4; ++n)
        acc[2 + m][n] = __builtin_amdgcn_mfma_f32_16x16x32_bf16(a1[m], b0[n], acc[2 + m][n], 0, 0, 0);
    __builtin_amdgcn_s_setprio(0);
    if (more) { asm volatile("s_waitcnt vmcnt(1)" ::: "memory"); }
    else      { asm volatile("s_waitcnt vmcnt(0)" ::: "memory"); }
    __builtin_amdgcn_s_barrier();
    __builtin_amdgcn_sched_barrier(0);

    bf16x8 a2[2], b2[4];
    #pragma unroll
    for (int m = 0; m < 2; ++m) a2[m] = lds_frag(smem, 24576, wm * 64 + m * 16 + rA, cg);
    #pragma unroll
    for (int n = 0; n < 4; ++n) b2[n] = lds_frag(smem, 24576 + 16384, wn * 64 + n * 16 + rA, cg);
    if (more) STAGE_A2(t + 2, 0);
    __builtin_amdgcn_s_barrier();
    asm volatile("s_waitcnt lgkmcnt(0)" ::: "memory");
    __builtin_amdgcn_sched_barrier(0);
    __builtin_amdgcn_s_setprio(1);
    #pragma unroll
    for (int m = 0; m < 2; ++m)
      #pragma unroll
      for (int n = 0; n < 4; ++n)
        acc[m][n] = __builtin_amdgcn_mfma_f32_16x16x32_bf16(a2[m], b2[n], acc[m][n], 0, 0, 0);
    __builtin_amdgcn_s_setprio(0);
    __builtin_amdgcn_s_barrier();
    __builtin_amdgcn_sched_barrier(0);

    bf16x8 a3[2];
    #pragma unroll
    for (int m = 0; m < 2; ++m) a3[m] = lds_frag(smem, 24576, wm * 64 + 32 + m * 16 + rA, cg);
    if (more) STAGE_B1(t + 3, 1);
    __builtin_amdgcn_s_barrier();
    asm volatile("s_waitcnt lgkmcnt(0)" ::: "memory");
    __builtin_amdgcn_sched_barrier(0);
    __builtin_amdgcn_s_setprio(1);
    #pragma unroll
    for (int m = 0; m < 2; ++m)
      #pragma unroll
      for (int n = 0; n < 4; ++n)
        acc[2 + m][n] = __builtin_amdgcn_mfma_f32_16x16x32_bf16(a3[m], b2[n], acc[2 + m][n], 0, 0, 0);
    __builtin_amdgcn_s_setprio(0);
    if (more) { asm volatile("s_waitcnt vmcnt(1)" ::: "memory"); }
    __builtin_amdgcn_s_barrier();
    __builtin_amdgcn_sched_barrier(0);
  }

  #pragma unroll
  for (int n = 0; n < 4; ++n) {
    int col = n0 + wn * 64 + n * 16 + (lane & 15);
    float bv = bias[col];
    #pragma unroll
    for (int m = 0; m < 4; ++m) {
      #pragma unroll
      for (int r = 0; r < 4; ++r) {
        int row = m0 + wm * 64 + m * 16 + (lane >> 4) * 4 + r;
        float v = fmaxf(acc[m][n][r] + bv, 0.f);
        C[(size_t)row * N + col] = f2bf(v);
      }
    }
  }
  #undef STAGE_A2
  #undef STAGE_B1
}

// ---------------- fused t3 GEMM (64x256 tile, N=256 K=512) + final dot ----------------
__global__ __launch_bounds__(256) void gemm_t3_final(
    const __bf16* __restrict__ A, const __bf16* __restrict__ WT,
    const float* __restrict__ b3, const float* __restrict__ w4,
    const float* __restrict__ b4, float* __restrict__ out)
{
  __shared__ __bf16 As[64][32];
  __shared__ __bf16 Bs[256][32];
  __shared__ float red[64][4];
  const int tid = threadIdx.x, lane = tid & 63, wid = tid >> 6;
  const int m0 = blockIdx.x * 64;
  const int srow = wid * 16 + (lane >> 2);
  const int scol = (lane & 3) * 8;
  const __bf16* Ag0 = A + (size_t)(m0 + srow) * 512 + scol;

  f32x4 acc[4][4] = {};

  for (int k0 = 0; k0 < 512; k0 += 32) {
    __syncthreads();
    GLDS16(Ag0 + k0, &As[srow][scol]);
    #pragma unroll
    for (int c = 0; c < 4; ++c) {
      int br = wid * 64 + c * 16 + (lane >> 2);
      GLDS16(WT + (size_t)br * 512 + k0 + scol, &Bs[br][scol]);
    }
    __syncthreads();

    bf16x8 af[4], bfv[4];
    #pragma unroll
    for (int m = 0; m < 4; ++m)
      af[m] = *(const bf16x8*)&As[m * 16 + (lane & 15)][(lane >> 4) * 8];
    #pragma unroll
    for (int n = 0; n < 4; ++n)
      bfv[n] = *(const bf16x8*)&Bs[wid * 64 + n * 16 + (lane & 15)][(lane >> 4) * 8];
    #pragma unroll
    for (int m = 0; m < 4; ++m)
      #pragma unroll
      for (int n = 0; n < 4; ++n)
        acc[m][n] = __builtin_amdgcn_mfma_f32_16x16x32_bf16(af[m], bfv[n], acc[m][n], 0, 0, 0);
  }

  float pd[4][4];
  #pragma unroll
  for (int m = 0; m < 4; ++m)
    #pragma unroll
    for (int r = 0; r < 4; ++r) pd[m][r] = 0.f;
  #pragma unroll
  for (int n = 0; n < 4; ++n) {
    int col = wid * 64 + n * 16 + (lane & 15);
    float bb = b3[col];
    float wc = w4[col];
    #pragma unroll
    for (int m = 0; m < 4; ++m)
      #pragma unroll
      for (int r = 0; r < 4; ++r)
        pd[m][r] += fmaxf(acc[m][n][r] + bb, 0.f) * wc;
  }
  #pragma unroll
  for (int m = 0; m < 4; ++m)
    #pragma unroll
    for (int r = 0; r < 4; ++r) {
      float s = pd[m][r];
      s += __shfl_xor(s, 1); s += __shfl_xor(s, 2);
      s += __shfl_xor(s, 4); s += __shfl_xor(s, 8);
      if ((lane & 15) == 0) red[m * 16 + (lane >> 4) * 4 + r][wid] = s;
    }
  __syncthreads();
  if (tid < 64)
    out[m0 + tid] = red[tid][0] + red[tid][1] + red[tid][2] + red[tid][3] + b4[0];
}

extern "C" void kernel_launch(void* const* d_in, const int* in_sizes, int n_in,
                              void* d_out, int out_size, void* d_ws, size_t ws_size,
                              hipStream_t stream)
{
  const float* x_dense = (const float*)d_in[0];
  const int*   x_cat   = (const int*)d_in[1];
  const float* emb     = (const float*)d_in[2];
  const float* wb[3] = {(const float*)d_in[3], (const float*)d_in[5], (const float*)d_in[7]};
  const float* bb[3] = {(const float*)d_in[4], (const float*)d_in[6], (const float*)d_in[8]};
  const float* wt[5] = {(const float*)d_in[9],  (const float*)d_in[11], (const float*)d_in[13],
                        (const float*)d_in[15], (const float*)d_in[17]};
  const float* bt[5] = {(const float*)d_in[10], (const float*)d_in[12], (const float*)d_in[14],
                        (const float*)d_in[16], (const float*)d_in[18]};
  float* out = (float*)d_out;

  char* ws = (char*)d_ws;
  const size_t MB = 1ull << 20;
  __bf16* wt_b0 = (__bf16*)(ws + 0 * MB);   // 512x32
  __bf16* wt_b1 = (__bf16*)(ws + 1 * MB);   // 256x512
  __bf16* wt_b2 = (__bf16*)(ws + 2 * MB);   // 128x256
  __bf16* wt_t0 = (__bf16*)(ws + 3 * MB);   // 1024x512
  __bf16* wt_t1 = (__bf16*)(ws + 4 * MB);   // 1024x1024
  __bf16* wt_t2 = (__bf16*)(ws + 6 * MB);   // 512x1024
  __bf16* wt_t3 = (__bf16*)(ws + 7 * MB);   // 256x512
  __bf16* h2     = (__bf16*)(ws + 8 * MB);   // 16384x128 = 4MB
  __bf16* top_in = (__bf16*)(ws + 12 * MB);  // 16MB (region C)
  __bf16* t2     = (__bf16*)(ws + 12 * MB);  // (region C, after top_in dead)
  __bf16* t1     = (__bf16*)(ws + 28 * MB);  // 32MB (region A)
  __bf16* t0     = (__bf16*)(ws + 60 * MB);  // 32MB (region B)

  // ---- fused weight prep (1 dispatch) ----
  TJobs js;
  const float* Ws[7] = {wb[0], wb[1], wb[2], wt[0], wt[1], wt[2], wt[3]};
  __bf16* WTs[7] = {wt_b0, wt_b1, wt_b2, wt_t0, wt_t1, wt_t2, wt_t3};
  int Ks[7]  = {13, 512, 256, 506, 1024, 1024, 512};
  int Ns[7]  = {512, 256, 128, 1024, 1024, 512, 256};
  int Kps[7] = {32, 512, 256, 512, 1024, 1024, 512};
  int off = 0;
  for (int i = 0; i < 7; ++i) {
    int tx = (Kps[i] + 63) / 64, ty = (Ns[i] + 63) / 64;
    js.j[i] = TJob{Ws[i], WTs[i], Ks[i], Ns[i], Kps[i], tx, off};
    off += tx * ty;
  }
  transpose_all<<<dim3(off), dim3(256), 0, stream>>>(js, 7);

  // ---- fused bottom MLP ----
  bottom_fused<<<dim3(BATCH / 32), dim3(256), 0, stream>>>(
      x_dense, wt_b0, bb[0], wt_b1, bb[1], wt_b2, bb[2], h2);

  // ---- embedding + interaction ----
  interact_mfma<<<dim3(BATCH / 4), dim3(256), 0, stream>>>(h2, x_cat, emb, top_in);

  // ---- top MLP ----
  gemm_8ph_bm128<<<dim3(512), dim3(512), 0, stream>>>(top_in, wt_t0, bt[0], t0, 1024, 512, 512, 128);
  gemm_8ph_bm128<<<dim3(512), dim3(512), 0, stream>>>(t0, wt_t1, bt[1], t1, 1024, 1024, 1024, 128);
  gemm_8ph_n128<<<dim3(256), dim3(512), 0, stream>>>(t1, wt_t2, bt[2], t2, 512, 1024, 1024, 64);

  // ---- fused t3 + final ----
  gemm_t3_final<<<dim3(256), dim3(256), 0, stream>>>(t2, wt_t3, bt[3], wt[4], bt[4], out);
}